// Round 10
// baseline (107.384 us; speedup 1.0000x reference)
//
#include <hip/hip_runtime.h>
#include <math.h>

#define NS 4096
#define NC 500
#define NF 256
#define NK 400
#define KC_GEMM 16     // split-K chunks (256 rows each)
#define NQJ 16000      // queue jobs: 8 rows each (128000 rows total)

// ---------------- kernel 1: fused heavy pass (software-pipelined hybrid) ----
// All 1024 blocks identical (no dispatch convoys — R6/R7 lesson):
//   - one GEMM job per block: P[kc][c0..c0+15][f] over a 256-row n-chunk,
//     Y tile staged in LDS (broadcast reads), X coalesced (R8-proven).
//   - 16 queue jobs per block (4/wave, 8 rows each): loads ISSUED before a
//     GEMM chunk, CONSUMED after it -> HBM streams under FMA (R9 lesson:
//     keep global latency off the critical loop).
//   - colsum partials computed from the staged ytile (free; colsum blocks
//     and their 16 MB of Y re-reads eliminated).
__global__ __launch_bounds__(256, 4) void k_heavy(
    const float* __restrict__ Xs, const float* __restrict__ Ys, float* __restrict__ Ps,
    const float* __restrict__ Xt, const float* __restrict__ Yt, float* __restrict__ Pt,
    float* __restrict__ CSs, float* __restrict__ CSt,
    const float* __restrict__ queue, const int* __restrict__ qsize,
    float* __restrict__ qsum) {
  __shared__ float ytile[256][16];              // 16 KB
  const int hb   = blockIdx.x;                  // 0..1023
  const int tid  = threadIdx.x;
  const int w    = tid >> 6;
  const int lane = tid & 63;

  // GEMM job: z = hb>>9, kc = (hb>>5)&15, ct = hb&31
  const int z  = hb >> 9;
  const int kc = (hb >> 5) & 15;
  const int c0 = (hb & 31) * 16;
  const float* X = z ? Xt : Xs;
  const float* Y = z ? Yt : Ys;
  float*       P = z ? Pt : Ps;
  float*      CS = z ? CSt : CSs;
  const int n0   = kc * 256;
  const int cmax = (NC - c0 < 16) ? (NC - c0) : 16;

  // queue pipeline state (all statically indexed -> registers)
  float4 ld0, ld1, ld2, ld3, ld4, ld5, ld6, ld7;
  float  s0 = 0.f, s1 = 0.f, s2 = 0.f, s3 = 0.f, s4 = 0.f, s5 = 0.f, s6 = 0.f, s7 = 0.f;
  const int qb = hb * 16 + w * 4;               // this wave's first queue job

  auto q_issue = [&](int q, int seg) {
    if (q >= NQJ) return;
    const int qs = qsize[q >> 5];
    const int L  = (qs + 3) >> 2;
    const int kidx = (seg << 6) + lane;
    if (kidx < L) {
      const float* base = queue + (size_t)(q << 3) * NK + (kidx << 2);
      ld0 = *reinterpret_cast<const float4*>(base + 0 * NK);
      ld1 = *reinterpret_cast<const float4*>(base + 1 * NK);
      ld2 = *reinterpret_cast<const float4*>(base + 2 * NK);
      ld3 = *reinterpret_cast<const float4*>(base + 3 * NK);
      ld4 = *reinterpret_cast<const float4*>(base + 4 * NK);
      ld5 = *reinterpret_cast<const float4*>(base + 5 * NK);
      ld6 = *reinterpret_cast<const float4*>(base + 6 * NK);
      ld7 = *reinterpret_cast<const float4*>(base + 7 * NK);
    }
  };
  auto q_consume = [&](int q, int seg) {
    if (q >= NQJ) return;
    const int qs = qsize[q >> 5];
    const int L  = (qs + 3) >> 2;
    if (seg == 0) { s0 = s1 = s2 = s3 = s4 = s5 = s6 = s7 = 0.f; }
    const int kidx = (seg << 6) + lane;
    if (kidx < L) {
      const int k = kidx << 2;
      s0 += ld0.x; s1 += ld1.x; s2 += ld2.x; s3 += ld3.x;
      s4 += ld4.x; s5 += ld5.x; s6 += ld6.x; s7 += ld7.x;
      if (k + 1 < qs) { s0 += ld0.y; s1 += ld1.y; s2 += ld2.y; s3 += ld3.y;
                        s4 += ld4.y; s5 += ld5.y; s6 += ld6.y; s7 += ld7.y; }
      if (k + 2 < qs) { s0 += ld0.z; s1 += ld1.z; s2 += ld2.z; s3 += ld3.z;
                        s4 += ld4.z; s5 += ld5.z; s6 += ld6.z; s7 += ld7.z; }
      if (k + 3 < qs) { s0 += ld0.w; s1 += ld1.w; s2 += ld2.w; s3 += ld3.w;
                        s4 += ld4.w; s5 += ld5.w; s6 += ld6.w; s7 += ld7.w; }
    }
  };
  auto q_finish = [&](int q) {
    if (q >= NQJ) return;
    #pragma unroll
    for (int m = 32; m; m >>= 1) {
      s0 += __shfl_xor(s0, m); s1 += __shfl_xor(s1, m);
      s2 += __shfl_xor(s2, m); s3 += __shfl_xor(s3, m);
      s4 += __shfl_xor(s4, m); s5 += __shfl_xor(s5, m);
      s6 += __shfl_xor(s6, m); s7 += __shfl_xor(s7, m);
    }
    if (lane == 0) {
      *reinterpret_cast<float4*>(&qsum[(q << 3)])     = make_float4(s0, s1, s2, s3);
      *reinterpret_cast<float4*>(&qsum[(q << 3) + 4]) = make_float4(s4, s5, s6, s7);
    }
  };

  // prologue: first queue seg streams while ytile stages
  q_issue(qb + 0, 0);

  for (int i = tid; i < 256 * 16; i += 256) {
    int rr = i >> 4, cc = i & 15;
    ytile[rr][cc] = (cc < cmax) ? Y[(size_t)(n0 + rr) * NC + c0 + cc] : 0.f;
  }
  __syncthreads();

  float acc[16];
  #pragma unroll
  for (int j = 0; j < 16; ++j) acc[j] = 0.f;
  const float* Xp = X + (size_t)n0 * NF + tid;

  auto gemm_chunk = [&](int ch) {
    const int nb = ch << 5;
    #pragma unroll 4
    for (int n = nb; n < nb + 32; ++n) {
      float xv = Xp[(size_t)n * NF];
      float4 y0 = *reinterpret_cast<const float4*>(&ytile[n][0]);
      float4 y1 = *reinterpret_cast<const float4*>(&ytile[n][4]);
      float4 y2 = *reinterpret_cast<const float4*>(&ytile[n][8]);
      float4 y3 = *reinterpret_cast<const float4*>(&ytile[n][12]);
      acc[0]  = fmaf(y0.x, xv, acc[0]);  acc[1]  = fmaf(y0.y, xv, acc[1]);
      acc[2]  = fmaf(y0.z, xv, acc[2]);  acc[3]  = fmaf(y0.w, xv, acc[3]);
      acc[4]  = fmaf(y1.x, xv, acc[4]);  acc[5]  = fmaf(y1.y, xv, acc[5]);
      acc[6]  = fmaf(y1.z, xv, acc[6]);  acc[7]  = fmaf(y1.w, xv, acc[7]);
      acc[8]  = fmaf(y2.x, xv, acc[8]);  acc[9]  = fmaf(y2.y, xv, acc[9]);
      acc[10] = fmaf(y2.z, xv, acc[10]); acc[11] = fmaf(y2.w, xv, acc[11]);
      acc[12] = fmaf(y3.x, xv, acc[12]); acc[13] = fmaf(y3.y, xv, acc[13]);
      acc[14] = fmaf(y3.z, xv, acc[14]); acc[15] = fmaf(y3.w, xv, acc[15]);
    }
  };

  // pipelined schedule: issue seg -> GEMM chunk (hides latency) -> consume
  gemm_chunk(0); q_consume(qb + 0, 0); q_issue(qb + 0, 1);
  gemm_chunk(1); q_consume(qb + 0, 1); q_finish(qb + 0); q_issue(qb + 1, 0);
  gemm_chunk(2); q_consume(qb + 1, 0); q_issue(qb + 1, 1);
  gemm_chunk(3); q_consume(qb + 1, 1); q_finish(qb + 1); q_issue(qb + 2, 0);
  gemm_chunk(4); q_consume(qb + 2, 0); q_issue(qb + 2, 1);
  gemm_chunk(5); q_consume(qb + 2, 1); q_finish(qb + 2); q_issue(qb + 3, 0);
  gemm_chunk(6); q_consume(qb + 3, 0); q_issue(qb + 3, 1);
  gemm_chunk(7); q_consume(qb + 3, 1); q_finish(qb + 3);

  // colsum partials from the staged ytile: wave w owns classes w*4..w*4+3
  #pragma unroll
  for (int j = 0; j < 4; ++j) {
    const int cc = w * 4 + j;
    float t = ytile[lane][cc] + ytile[lane + 64][cc]
            + ytile[lane + 128][cc] + ytile[lane + 192][cc];
    #pragma unroll
    for (int m = 32; m; m >>= 1) t += __shfl_xor(t, m);
    if (lane == 0) CS[kc * 512 + c0 + cc] = t;
  }

  // GEMM epilogue
  #pragma unroll
  for (int j = 0; j < 16; ++j)
    if (j < cmax) P[((size_t)kc * NC + c0 + j) * NF + tid] = acc[j];
}

// ---------------- kernel 2: finalize means + intra diagonal ----------------
// wave per class (4 classes/block), float4 per lane over features
__global__ __launch_bounds__(256) void k_means(
    const float* __restrict__ qsum, const int* __restrict__ qsize,
    const float* __restrict__ Psrc, const float* __restrict__ Ptgt,
    const float* __restrict__ CSsrc, const float* __restrict__ CStgt,
    float* __restrict__ MS, float* __restrict__ MT, float* __restrict__ ipart) {
  const int c = blockIdx.x * 4 + (threadIdx.x >> 6);
  const int lane = threadIdx.x & 63;
  const int f4 = lane * 4;
  if (c >= NC) return;

  float cs_s = 0.f, cs_t = 0.f;
  #pragma unroll
  for (int kc = 0; kc < KC_GEMM; ++kc) {
    cs_s += CSsrc[kc * 512 + c];
    cs_t += CStgt[kc * 512 + c];
  }
  float num = (float)qsize[c];
  float4 ns = *reinterpret_cast<const float4*>(&qsum[(size_t)c * NF + f4]);
  float4 nt = make_float4(0.f, 0.f, 0.f, 0.f);
  #pragma unroll
  for (int kc = 0; kc < KC_GEMM; ++kc) {
    float4 ps = *reinterpret_cast<const float4*>(&Psrc[((size_t)kc * NC + c) * NF + f4]);
    float4 pt = *reinterpret_cast<const float4*>(&Ptgt[((size_t)kc * NC + c) * NF + f4]);
    ns.x += ps.x; ns.y += ps.y; ns.z += ps.z; ns.w += ps.w;
    nt.x += pt.x; nt.y += pt.y; nt.z += pt.z; nt.w += pt.w;
  }
  float rs = 1.f / (num + cs_s + 1e-8f);
  float rt = 1.f / (cs_t + 1e-8f);
  float4 ms = make_float4(ns.x * rs, ns.y * rs, ns.z * rs, ns.w * rs);
  float4 mt = make_float4(nt.x * rt, nt.y * rt, nt.z * rt, nt.w * rt);
  *reinterpret_cast<float4*>(&MS[(size_t)c * NF + f4]) = ms;
  *reinterpret_cast<float4*>(&MT[(size_t)c * NF + f4]) = mt;

  float dx = ms.x - mt.x, dy = ms.y - mt.y, dz = ms.z - mt.z, dw = ms.w - mt.w;
  float s = dx * dx + dy * dy + dz * dz + dw * dw;
  #pragma unroll
  for (int m = 32; m; m >>= 1) s += __shfl_xor(s, m);
  if (lane == 0) ipart[c] = sqrtf(fmaxf(s, 1e-12f));
}

// ---------------- kernel 3: pairwise distances (16x16 tiles) ----------------
#define TC 16
#define NBT 32                              // ceil(500/16)
__global__ __launch_bounds__(256) void k_dist(const float* __restrict__ MS,
                                              float* __restrict__ epart) {
  __shared__ float a[TC][NF + 4];
  __shared__ float b[TC][NF + 4];
  const int bi = blockIdx.x & (NBT - 1);
  const int bj = blockIdx.x >> 5;

  for (int i = threadIdx.x; i < TC * (NF / 4); i += 256) {
    int rr = i >> 6, fq = (i & 63) * 4;
    int c1 = bi * TC + rr;
    int c2 = bj * TC + rr;
    float4 va = (c1 < NC) ? *reinterpret_cast<const float4*>(&MS[(size_t)c1 * NF + fq])
                          : make_float4(0.f, 0.f, 0.f, 0.f);
    float4 vb = (c2 < NC) ? *reinterpret_cast<const float4*>(&MS[(size_t)c2 * NF + fq])
                          : make_float4(0.f, 0.f, 0.f, 0.f);
    *reinterpret_cast<float4*>(&a[rr][fq]) = va;
    *reinterpret_cast<float4*>(&b[rr][fq]) = vb;
  }
  __syncthreads();

  const int i1 = threadIdx.x >> 4, i2 = threadIdx.x & 15;
  float s = 0.f;
  #pragma unroll 8
  for (int fq = 0; fq < NF; fq += 4) {
    float4 va = *reinterpret_cast<const float4*>(&a[i1][fq]);
    float4 vb = *reinterpret_cast<const float4*>(&b[i2][fq]);
    float d0 = va.x - vb.x, d1 = va.y - vb.y, d2 = va.z - vb.z, d3 = va.w - vb.w;
    s = fmaf(d0, d0, s); s = fmaf(d1, d1, s); s = fmaf(d2, d2, s); s = fmaf(d3, d3, s);
  }
  bool valid = (bi * TC + i1 < NC) && (bj * TC + i2 < NC);
  float rr = valid ? sqrtf(fmaxf(s, 1e-12f)) : 0.f;

  #pragma unroll
  for (int m = 32; m; m >>= 1) rr += __shfl_xor(rr, m);
  __shared__ float red[4];
  int wid = threadIdx.x >> 6, lane = threadIdx.x & 63;
  if (lane == 0) red[wid] = rr;
  __syncthreads();
  if (threadIdx.x == 0) epart[blockIdx.x] = red[0] + red[1] + red[2] + red[3];
}

// ---------------- kernel 4: final scalars ----------------
__global__ __launch_bounds__(1024) void k_final(const float* __restrict__ ipart,
                                                const float* __restrict__ epart,
                                                float* __restrict__ out) {
  const int t = threadIdx.x;                // 1024 threads
  float si = (t < NC) ? ipart[t] : 0.f;
  float se = epart[t];
  #pragma unroll
  for (int m = 32; m; m >>= 1) { si += __shfl_xor(si, m); se += __shfl_xor(se, m); }
  __shared__ float ri[16], re[16];
  int wid = t >> 6, lane = t & 63;
  if (lane == 0) { ri[wid] = si; re[wid] = se; }
  __syncthreads();
  if (t == 0) {
    float A = 0.f, B = 0.f;
    #pragma unroll
    for (int w2 = 0; w2 < 16; ++w2) { A += ri[w2]; B += re[w2]; }
    out[0] = A / (float)NC;
    out[1] = B / ((float)NC * (float)NC);
  }
}

extern "C" void kernel_launch(void* const* d_in, const int* in_sizes, int n_in,
                              void* d_out, int out_size, void* d_ws, size_t ws_size,
                              hipStream_t stream) {
  const float* src_x = (const float*)d_in[0];
  const float* tgt_x = (const float*)d_in[1];
  const float* src_y = (const float*)d_in[2];
  const float* tgt_y = (const float*)d_in[3];
  const float* queue = (const float*)d_in[4];
  const int*   qsize = (const int*)d_in[5];
  float* out = (float*)d_out;

  float* ws    = (float*)d_ws;
  float* qsum  = ws;                                   // 128000
  float* Psrc  = qsum + NC * NF;                       // 16 * 128000
  float* Ptgt  = Psrc + (size_t)KC_GEMM * NC * NF;     // 16 * 128000
  float* CSs   = Ptgt + (size_t)KC_GEMM * NC * NF;     // 16 * 512
  float* CSt   = CSs + KC_GEMM * 512;                  // 16 * 512
  float* MS    = CSt + KC_GEMM * 512;                  // 128000
  float* MT    = MS + NC * NF;                         // 128000
  float* ipart = MT + NC * NF;                         // 500
  float* epart = ipart + NC;                           // 1024

  // 1) fused heavy pass: 1024 identical hybrid blocks (gemm + queue + colsum)
  k_heavy<<<1024, 256, 0, stream>>>(
      src_x, src_y, Psrc, tgt_x, tgt_y, Ptgt, CSs, CSt, queue, qsize, qsum);

  // 2) means + intra diagonal (wave per class)
  k_means<<<(NC + 3) / 4, 256, 0, stream>>>(qsum, qsize, Psrc, Ptgt, CSs, CSt, MS, MT, ipart);

  // 3) pairwise distances
  k_dist<<<NBT * NBT, 256, 0, stream>>>(MS, epart);

  // 4) final reduction
  k_final<<<1, 1024, 0, stream>>>(ipart, epart, out);
}

// Round 11
// 83.527 us; speedup vs baseline: 1.2856x; 1.2856x over previous
//
#include <hip/hip_runtime.h>
#include <math.h>

#define NS 4096
#define NC 500
#define NF 256
#define NK 400
#define KC_GEMM 16     // split-K chunks (256 rows each)
#define NQB 4000       // queue block-jobs (32 rows each)

// ---------------- kernel 1: fused heavy pass (persistent, phase-staggered) --
// 1024 persistent blocks (4/CU). Block b runs 5 iterations: iteration (b%5)
// is its GEMM job (R8-proven LDS-broadcast tile); the other 4 are queue jobs
// (R8-proven 8-rows-per-wave). Blocks co-resident on a CU differ by 256 ==
// 1 (mod 5), so each CU always holds ~1 VALU-heavy block + ~3 HBM-streaming
// blocks: pipe overlap by construction, independent of dispatch order
// (R6/R7/R10 lessons). Colsum is accumulated during ytile staging (cc=tid&15
// is per-thread constant -> no LDS conflicts, no Y re-read).
__global__ __launch_bounds__(256, 4) void k_heavy(
    const float* __restrict__ Xs, const float* __restrict__ Ys, float* __restrict__ Ps,
    const float* __restrict__ Xt, const float* __restrict__ Yt, float* __restrict__ Pt,
    float* __restrict__ CSs, float* __restrict__ CSt,
    const float* __restrict__ queue, const int* __restrict__ qsize,
    float* __restrict__ qsum) {
  __shared__ float ytile[256][16];              // 16 KB
  __shared__ float csbuf[256];                  // colsum partials
  const int b    = blockIdx.x;                  // 0..1023
  const int tid  = threadIdx.x;
  const int w    = tid >> 6;
  const int lane = tid & 63;
  const int hp   = b % 5;                       // this block's heavy phase

  for (int it = 0; it < 5; ++it) {
    if (it == hp) {
      // ---- GEMM job b: P[kc][c0..c0+15][f] over 256-row n-chunk ----
      const int z  = b >> 9;
      const int kc = (b >> 5) & 15;
      const int c0 = (b & 31) * 16;
      const float* X = z ? Xt : Xs;
      const float* Y = z ? Yt : Ys;
      float*       P = z ? Pt : Ps;
      float*      CS = z ? CSt : CSs;
      const int n0   = kc * 256;
      const int cmax = (NC - c0 < 16) ? (NC - c0) : 16;

      // stage Y tile + accumulate colsum partial (cc = tid&15, fixed)
      float csum = 0.f;
      for (int i = tid; i < 256 * 16; i += 256) {
        int rr = i >> 4, cc = i & 15;
        float v = (cc < cmax) ? Y[(size_t)(n0 + rr) * NC + c0 + cc] : 0.f;
        ytile[rr][cc] = v;
        csum += v;
      }
      csbuf[tid] = csum;
      __syncthreads();

      float acc[16];
      #pragma unroll
      for (int j = 0; j < 16; ++j) acc[j] = 0.f;
      const float* Xp = X + (size_t)n0 * NF + tid;

      #pragma unroll 4
      for (int n = 0; n < 256; ++n) {
        float xv = Xp[(size_t)n * NF];
        float4 y0 = *reinterpret_cast<const float4*>(&ytile[n][0]);
        float4 y1 = *reinterpret_cast<const float4*>(&ytile[n][4]);
        float4 y2 = *reinterpret_cast<const float4*>(&ytile[n][8]);
        float4 y3 = *reinterpret_cast<const float4*>(&ytile[n][12]);
        acc[0]  = fmaf(y0.x, xv, acc[0]);  acc[1]  = fmaf(y0.y, xv, acc[1]);
        acc[2]  = fmaf(y0.z, xv, acc[2]);  acc[3]  = fmaf(y0.w, xv, acc[3]);
        acc[4]  = fmaf(y1.x, xv, acc[4]);  acc[5]  = fmaf(y1.y, xv, acc[5]);
        acc[6]  = fmaf(y1.z, xv, acc[6]);  acc[7]  = fmaf(y1.w, xv, acc[7]);
        acc[8]  = fmaf(y2.x, xv, acc[8]);  acc[9]  = fmaf(y2.y, xv, acc[9]);
        acc[10] = fmaf(y2.z, xv, acc[10]); acc[11] = fmaf(y2.w, xv, acc[11]);
        acc[12] = fmaf(y3.x, xv, acc[12]); acc[13] = fmaf(y3.y, xv, acc[13]);
        acc[14] = fmaf(y3.z, xv, acc[14]); acc[15] = fmaf(y3.w, xv, acc[15]);
      }

      // colsum reduce: thread cc<16 sums csbuf[cc + 16*j] (csbuf is stable)
      if (tid < 16) {
        float t = 0.f;
        #pragma unroll
        for (int j = 0; j < 16; ++j) t += csbuf[tid + 16 * j];
        CS[kc * 512 + c0 + tid] = t;
      }

      // GEMM epilogue
      #pragma unroll
      for (int j = 0; j < 16; ++j)
        if (j < cmax) P[((size_t)kc * NC + c0 + j) * NF + tid] = acc[j];
      __syncthreads();                          // ytile/csbuf done

    } else {
      // ---- queue job: 32 rows, wave w owns 8 rows (R8-proven body) ----
      const int j = it - (it > hp ? 1 : 0);     // 0..3
      const int q = j * 1024 + b;
      if (q < NQB) {
        const int r0 = q * 32 + w * 8;          // 8 consecutive rows, one class
        const int c  = r0 >> 8;
        const int qs = qsize[c];
        const int L  = (qs + 3) >> 2;           // float4s needed (<=100)
        const float* base = queue + (size_t)r0 * NK;
        float s0 = 0.f, s1 = 0.f, s2 = 0.f, s3 = 0.f;
        float s4 = 0.f, s5 = 0.f, s6 = 0.f, s7 = 0.f;

        if (lane < L) {
          const int k = 4 * lane;               // 0..255, k < qs guaranteed
          float4 v0 = *reinterpret_cast<const float4*>(base + 0 * NK + k);
          float4 v1 = *reinterpret_cast<const float4*>(base + 1 * NK + k);
          float4 v2 = *reinterpret_cast<const float4*>(base + 2 * NK + k);
          float4 v3 = *reinterpret_cast<const float4*>(base + 3 * NK + k);
          float4 v4 = *reinterpret_cast<const float4*>(base + 4 * NK + k);
          float4 v5 = *reinterpret_cast<const float4*>(base + 5 * NK + k);
          float4 v6 = *reinterpret_cast<const float4*>(base + 6 * NK + k);
          float4 v7 = *reinterpret_cast<const float4*>(base + 7 * NK + k);
          s0 += v0.x; s1 += v1.x; s2 += v2.x; s3 += v3.x;
          s4 += v4.x; s5 += v5.x; s6 += v6.x; s7 += v7.x;
          if (k + 1 < qs) { s0 += v0.y; s1 += v1.y; s2 += v2.y; s3 += v3.y;
                            s4 += v4.y; s5 += v5.y; s6 += v6.y; s7 += v7.y; }
          if (k + 2 < qs) { s0 += v0.z; s1 += v1.z; s2 += v2.z; s3 += v3.z;
                            s4 += v4.z; s5 += v5.z; s6 += v6.z; s7 += v7.z; }
          if (k + 3 < qs) { s0 += v0.w; s1 += v1.w; s2 += v2.w; s3 += v3.w;
                            s4 += v4.w; s5 += v5.w; s6 += v6.w; s7 += v7.w; }
        }
        if (lane + 64 < L) {
          const int k = 256 + 4 * lane;         // 256..399
          float4 v0 = *reinterpret_cast<const float4*>(base + 0 * NK + k);
          float4 v1 = *reinterpret_cast<const float4*>(base + 1 * NK + k);
          float4 v2 = *reinterpret_cast<const float4*>(base + 2 * NK + k);
          float4 v3 = *reinterpret_cast<const float4*>(base + 3 * NK + k);
          float4 v4 = *reinterpret_cast<const float4*>(base + 4 * NK + k);
          float4 v5 = *reinterpret_cast<const float4*>(base + 5 * NK + k);
          float4 v6 = *reinterpret_cast<const float4*>(base + 6 * NK + k);
          float4 v7 = *reinterpret_cast<const float4*>(base + 7 * NK + k);
          s0 += v0.x; s1 += v1.x; s2 += v2.x; s3 += v3.x;
          s4 += v4.x; s5 += v5.x; s6 += v6.x; s7 += v7.x;
          if (k + 1 < qs) { s0 += v0.y; s1 += v1.y; s2 += v2.y; s3 += v3.y;
                            s4 += v4.y; s5 += v5.y; s6 += v6.y; s7 += v7.y; }
          if (k + 2 < qs) { s0 += v0.z; s1 += v1.z; s2 += v2.z; s3 += v3.z;
                            s4 += v4.z; s5 += v5.z; s6 += v6.z; s7 += v7.z; }
          if (k + 3 < qs) { s0 += v0.w; s1 += v1.w; s2 += v2.w; s3 += v3.w;
                            s4 += v4.w; s5 += v5.w; s6 += v6.w; s7 += v7.w; }
        }
        #pragma unroll
        for (int m = 32; m; m >>= 1) {
          s0 += __shfl_xor(s0, m); s1 += __shfl_xor(s1, m);
          s2 += __shfl_xor(s2, m); s3 += __shfl_xor(s3, m);
          s4 += __shfl_xor(s4, m); s5 += __shfl_xor(s5, m);
          s6 += __shfl_xor(s6, m); s7 += __shfl_xor(s7, m);
        }
        if (lane == 0) {
          *reinterpret_cast<float4*>(&qsum[r0])     = make_float4(s0, s1, s2, s3);
          *reinterpret_cast<float4*>(&qsum[r0 + 4]) = make_float4(s4, s5, s6, s7);
        }
      }
    }
  }
}

// ---------------- kernel 2: finalize means + intra diagonal ----------------
// wave per class (4 classes/block), float4 per lane over features
__global__ __launch_bounds__(256) void k_means(
    const float* __restrict__ qsum, const int* __restrict__ qsize,
    const float* __restrict__ Psrc, const float* __restrict__ Ptgt,
    const float* __restrict__ CSsrc, const float* __restrict__ CStgt,
    float* __restrict__ MS, float* __restrict__ MT, float* __restrict__ ipart) {
  const int c = blockIdx.x * 4 + (threadIdx.x >> 6);
  const int lane = threadIdx.x & 63;
  const int f4 = lane * 4;
  if (c >= NC) return;

  float cs_s = 0.f, cs_t = 0.f;
  #pragma unroll
  for (int kc = 0; kc < KC_GEMM; ++kc) {
    cs_s += CSsrc[kc * 512 + c];
    cs_t += CStgt[kc * 512 + c];
  }
  float num = (float)qsize[c];
  float4 ns = *reinterpret_cast<const float4*>(&qsum[(size_t)c * NF + f4]);
  float4 nt = make_float4(0.f, 0.f, 0.f, 0.f);
  #pragma unroll
  for (int kc = 0; kc < KC_GEMM; ++kc) {
    float4 ps = *reinterpret_cast<const float4*>(&Psrc[((size_t)kc * NC + c) * NF + f4]);
    float4 pt = *reinterpret_cast<const float4*>(&Ptgt[((size_t)kc * NC + c) * NF + f4]);
    ns.x += ps.x; ns.y += ps.y; ns.z += ps.z; ns.w += ps.w;
    nt.x += pt.x; nt.y += pt.y; nt.z += pt.z; nt.w += pt.w;
  }
  float rs = 1.f / (num + cs_s + 1e-8f);
  float rt = 1.f / (cs_t + 1e-8f);
  float4 ms = make_float4(ns.x * rs, ns.y * rs, ns.z * rs, ns.w * rs);
  float4 mt = make_float4(nt.x * rt, nt.y * rt, nt.z * rt, nt.w * rt);
  *reinterpret_cast<float4*>(&MS[(size_t)c * NF + f4]) = ms;
  *reinterpret_cast<float4*>(&MT[(size_t)c * NF + f4]) = mt;

  float dx = ms.x - mt.x, dy = ms.y - mt.y, dz = ms.z - mt.z, dw = ms.w - mt.w;
  float s = dx * dx + dy * dy + dz * dz + dw * dw;
  #pragma unroll
  for (int m = 32; m; m >>= 1) s += __shfl_xor(s, m);
  if (lane == 0) ipart[c] = sqrtf(fmaxf(s, 1e-12f));
}

// ---------------- kernel 3: pairwise distances (16x16 tiles) ----------------
#define TC 16
#define NBT 32                              // ceil(500/16)
__global__ __launch_bounds__(256) void k_dist(const float* __restrict__ MS,
                                              float* __restrict__ epart) {
  __shared__ float a[TC][NF + 4];
  __shared__ float b[TC][NF + 4];
  const int bi = blockIdx.x & (NBT - 1);
  const int bj = blockIdx.x >> 5;

  for (int i = threadIdx.x; i < TC * (NF / 4); i += 256) {
    int rr = i >> 6, fq = (i & 63) * 4;
    int c1 = bi * TC + rr;
    int c2 = bj * TC + rr;
    float4 va = (c1 < NC) ? *reinterpret_cast<const float4*>(&MS[(size_t)c1 * NF + fq])
                          : make_float4(0.f, 0.f, 0.f, 0.f);
    float4 vb = (c2 < NC) ? *reinterpret_cast<const float4*>(&MS[(size_t)c2 * NF + fq])
                          : make_float4(0.f, 0.f, 0.f, 0.f);
    *reinterpret_cast<float4*>(&a[rr][fq]) = va;
    *reinterpret_cast<float4*>(&b[rr][fq]) = vb;
  }
  __syncthreads();

  const int i1 = threadIdx.x >> 4, i2 = threadIdx.x & 15;
  float s = 0.f;
  #pragma unroll 8
  for (int fq = 0; fq < NF; fq += 4) {
    float4 va = *reinterpret_cast<const float4*>(&a[i1][fq]);
    float4 vb = *reinterpret_cast<const float4*>(&b[i2][fq]);
    float d0 = va.x - vb.x, d1 = va.y - vb.y, d2 = va.z - vb.z, d3 = va.w - vb.w;
    s = fmaf(d0, d0, s); s = fmaf(d1, d1, s); s = fmaf(d2, d2, s); s = fmaf(d3, d3, s);
  }
  bool valid = (bi * TC + i1 < NC) && (bj * TC + i2 < NC);
  float rr = valid ? sqrtf(fmaxf(s, 1e-12f)) : 0.f;

  #pragma unroll
  for (int m = 32; m; m >>= 1) rr += __shfl_xor(rr, m);
  __shared__ float red[4];
  int wid = threadIdx.x >> 6, lane = threadIdx.x & 63;
  if (lane == 0) red[wid] = rr;
  __syncthreads();
  if (threadIdx.x == 0) epart[blockIdx.x] = red[0] + red[1] + red[2] + red[3];
}

// ---------------- kernel 4: final scalars ----------------
__global__ __launch_bounds__(1024) void k_final(const float* __restrict__ ipart,
                                                const float* __restrict__ epart,
                                                float* __restrict__ out) {
  const int t = threadIdx.x;                // 1024 threads
  float si = (t < NC) ? ipart[t] : 0.f;
  float se = epart[t];
  #pragma unroll
  for (int m = 32; m; m >>= 1) { si += __shfl_xor(si, m); se += __shfl_xor(se, m); }
  __shared__ float ri[16], re[16];
  int wid = t >> 6, lane = t & 63;
  if (lane == 0) { ri[wid] = si; re[wid] = se; }
  __syncthreads();
  if (t == 0) {
    float A = 0.f, B = 0.f;
    #pragma unroll
    for (int w2 = 0; w2 < 16; ++w2) { A += ri[w2]; B += re[w2]; }
    out[0] = A / (float)NC;
    out[1] = B / ((float)NC * (float)NC);
  }
}

extern "C" void kernel_launch(void* const* d_in, const int* in_sizes, int n_in,
                              void* d_out, int out_size, void* d_ws, size_t ws_size,
                              hipStream_t stream) {
  const float* src_x = (const float*)d_in[0];
  const float* tgt_x = (const float*)d_in[1];
  const float* src_y = (const float*)d_in[2];
  const float* tgt_y = (const float*)d_in[3];
  const float* queue = (const float*)d_in[4];
  const int*   qsize = (const int*)d_in[5];
  float* out = (float*)d_out;

  float* ws    = (float*)d_ws;
  float* qsum  = ws;                                   // 128000
  float* Psrc  = qsum + NC * NF;                       // 16 * 128000
  float* Ptgt  = Psrc + (size_t)KC_GEMM * NC * NF;     // 16 * 128000
  float* CSs   = Ptgt + (size_t)KC_GEMM * NC * NF;     // 16 * 512
  float* CSt   = CSs + KC_GEMM * 512;                  // 16 * 512
  float* MS    = CSt + KC_GEMM * 512;                  // 128000
  float* MT    = MS + NC * NF;                         // 128000
  float* ipart = MT + NC * NF;                         // 500
  float* epart = ipart + NC;                           // 1024

  // 1) fused heavy pass: 1024 persistent phase-staggered hybrid blocks
  k_heavy<<<1024, 256, 0, stream>>>(
      src_x, src_y, Psrc, tgt_x, tgt_y, Ptgt, CSs, CSt, queue, qsize, qsum);

  // 2) means + intra diagonal (wave per class)
  k_means<<<(NC + 3) / 4, 256, 0, stream>>>(qsum, qsize, Psrc, Ptgt, CSs, CSt, MS, MT, ipart);

  // 3) pairwise distances
  k_dist<<<NBT * NBT, 256, 0, stream>>>(MS, epart);

  // 4) final reduction
  k_final<<<1, 1024, 0, stream>>>(ipart, epart, out);
}

// Round 12
// 82.850 us; speedup vs baseline: 1.2961x; 1.0082x over previous
//
#include <hip/hip_runtime.h>
#include <math.h>

#define NS 4096
#define NC 500
#define NF 256
#define NK 400
#define KC_GEMM 8      // split-K chunks (512 rows each)
#define NB_GEMM (KC_GEMM * 32 * 2)        // 512 gemm blocks
#define NQB 4000       // queue block-jobs (32 rows each)

// ---------------- kernel 1: fused heavy pass (R8 contiguous schedule) -------
// [0,512) gemm blocks | [512,4512) queue blocks. Contiguous mapping is the
// measured best (R5/R8); interleave/stagger schemes (R6/R7/R9/R10/R11) all
// regressed or tied. GEMM: 16 classes x 512 rows per block, two 256-row LDS
// passes (16 KB); colsum folded into staging (no extra Y read, no conflicts).
__global__ __launch_bounds__(256) void k_heavy(
    const float* __restrict__ Xs, const float* __restrict__ Ys, float* __restrict__ Ps,
    const float* __restrict__ Xt, const float* __restrict__ Yt, float* __restrict__ Pt,
    float* __restrict__ CSs, float* __restrict__ CSt,
    const float* __restrict__ queue, const int* __restrict__ qsize,
    float* __restrict__ qsum) {
  __shared__ float ytile[256][16];              // 16 KB
  __shared__ float csbuf[256];
  const int bid  = blockIdx.x;
  const int tid  = threadIdx.x;
  const int w    = tid >> 6;
  const int lane = tid & 63;

  if (bid < NB_GEMM) {
    // ---- GEMM partials: P[kc][c0..c0+15][f] over a 512-row n-chunk ----
    const int z   = bid >> 8;                   // 0:src 1:tgt
    const int rem = bid & 255;
    const int kc  = rem >> 5;                   // 0..7
    const int c0  = (rem & 31) * 16;
    const float* X = z ? Xt : Xs;
    const float* Y = z ? Yt : Ys;
    float*       P = z ? Pt : Ps;
    float*      CS = z ? CSt : CSs;
    const int n0   = kc * 512;
    const int cmax = (NC - c0 < 16) ? (NC - c0) : 16;

    float acc[16];
    #pragma unroll
    for (int j = 0; j < 16; ++j) acc[j] = 0.f;
    float csum = 0.f;

    for (int p = 0; p < 2; ++p) {
      // stage 256 rows + accumulate colsum partial (cc = tid&15 fixed/thread)
      {
        const int rr = tid >> 4, cc = tid & 15;
        #pragma unroll
        for (int j = 0; j < 16; ++j) {
          float v = (cc < cmax)
              ? Y[(size_t)(n0 + p * 256 + rr + 16 * j) * NC + c0 + cc] : 0.f;
          ytile[rr + 16 * j][cc] = v;
          csum += v;
        }
      }
      __syncthreads();

      const float* Xp = X + (size_t)(n0 + p * 256) * NF + tid;
      #pragma unroll 4
      for (int n = 0; n < 256; ++n) {
        float xv = Xp[(size_t)n * NF];
        float4 y0 = *reinterpret_cast<const float4*>(&ytile[n][0]);
        float4 y1 = *reinterpret_cast<const float4*>(&ytile[n][4]);
        float4 y2 = *reinterpret_cast<const float4*>(&ytile[n][8]);
        float4 y3 = *reinterpret_cast<const float4*>(&ytile[n][12]);
        acc[0]  = fmaf(y0.x, xv, acc[0]);  acc[1]  = fmaf(y0.y, xv, acc[1]);
        acc[2]  = fmaf(y0.z, xv, acc[2]);  acc[3]  = fmaf(y0.w, xv, acc[3]);
        acc[4]  = fmaf(y1.x, xv, acc[4]);  acc[5]  = fmaf(y1.y, xv, acc[5]);
        acc[6]  = fmaf(y1.z, xv, acc[6]);  acc[7]  = fmaf(y1.w, xv, acc[7]);
        acc[8]  = fmaf(y2.x, xv, acc[8]);  acc[9]  = fmaf(y2.y, xv, acc[9]);
        acc[10] = fmaf(y2.z, xv, acc[10]); acc[11] = fmaf(y2.w, xv, acc[11]);
        acc[12] = fmaf(y3.x, xv, acc[12]); acc[13] = fmaf(y3.y, xv, acc[13]);
        acc[14] = fmaf(y3.z, xv, acc[14]); acc[15] = fmaf(y3.w, xv, acc[15]);
      }
      __syncthreads();                          // before next stage overwrites
    }

    // colsum reduce: csbuf[tid] holds per-thread partial for class (tid&15)
    csbuf[tid] = csum;
    __syncthreads();
    if (tid < 16) {
      float t = 0.f;
      #pragma unroll
      for (int j = 0; j < 16; ++j) t += csbuf[tid + 16 * j];
      CS[kc * 512 + c0 + tid] = t;
    }

    // GEMM epilogue
    #pragma unroll
    for (int j = 0; j < 16; ++j)
      if (j < cmax) P[((size_t)kc * NC + c0 + j) * NF + tid] = acc[j];

  } else {
    // ---- masked queue reduction, tail-skip, 8 rows per wave (R8-proven) ----
    const int qb = bid - NB_GEMM;
    const int r0 = (qb * 4 + w) * 8;            // 8 consecutive rows, one class
    const int c  = r0 >> 8;
    const int qs = qsize[c];
    const int L  = (qs + 3) >> 2;               // float4s needed (<=100)
    const float* base = queue + (size_t)r0 * NK;
    float s0 = 0.f, s1 = 0.f, s2 = 0.f, s3 = 0.f;
    float s4 = 0.f, s5 = 0.f, s6 = 0.f, s7 = 0.f;

    if (lane < L) {
      const int k = 4 * lane;                   // 0..255, k < qs guaranteed
      float4 v0 = *reinterpret_cast<const float4*>(base + 0 * NK + k);
      float4 v1 = *reinterpret_cast<const float4*>(base + 1 * NK + k);
      float4 v2 = *reinterpret_cast<const float4*>(base + 2 * NK + k);
      float4 v3 = *reinterpret_cast<const float4*>(base + 3 * NK + k);
      float4 v4 = *reinterpret_cast<const float4*>(base + 4 * NK + k);
      float4 v5 = *reinterpret_cast<const float4*>(base + 5 * NK + k);
      float4 v6 = *reinterpret_cast<const float4*>(base + 6 * NK + k);
      float4 v7 = *reinterpret_cast<const float4*>(base + 7 * NK + k);
      s0 += v0.x; s1 += v1.x; s2 += v2.x; s3 += v3.x;
      s4 += v4.x; s5 += v5.x; s6 += v6.x; s7 += v7.x;
      if (k + 1 < qs) { s0 += v0.y; s1 += v1.y; s2 += v2.y; s3 += v3.y;
                        s4 += v4.y; s5 += v5.y; s6 += v6.y; s7 += v7.y; }
      if (k + 2 < qs) { s0 += v0.z; s1 += v1.z; s2 += v2.z; s3 += v3.z;
                        s4 += v4.z; s5 += v5.z; s6 += v6.z; s7 += v7.z; }
      if (k + 3 < qs) { s0 += v0.w; s1 += v1.w; s2 += v2.w; s3 += v3.w;
                        s4 += v4.w; s5 += v5.w; s6 += v6.w; s7 += v7.w; }
    }
    if (lane + 64 < L) {
      const int k = 256 + 4 * lane;             // 256..399
      float4 v0 = *reinterpret_cast<const float4*>(base + 0 * NK + k);
      float4 v1 = *reinterpret_cast<const float4*>(base + 1 * NK + k);
      float4 v2 = *reinterpret_cast<const float4*>(base + 2 * NK + k);
      float4 v3 = *reinterpret_cast<const float4*>(base + 3 * NK + k);
      float4 v4 = *reinterpret_cast<const float4*>(base + 4 * NK + k);
      float4 v5 = *reinterpret_cast<const float4*>(base + 5 * NK + k);
      float4 v6 = *reinterpret_cast<const float4*>(base + 6 * NK + k);
      float4 v7 = *reinterpret_cast<const float4*>(base + 7 * NK + k);
      s0 += v0.x; s1 += v1.x; s2 += v2.x; s3 += v3.x;
      s4 += v4.x; s5 += v5.x; s6 += v6.x; s7 += v7.x;
      if (k + 1 < qs) { s0 += v0.y; s1 += v1.y; s2 += v2.y; s3 += v3.y;
                        s4 += v4.y; s5 += v5.y; s6 += v6.y; s7 += v7.y; }
      if (k + 2 < qs) { s0 += v0.z; s1 += v1.z; s2 += v2.z; s3 += v3.z;
                        s4 += v4.z; s5 += v5.z; s6 += v6.z; s7 += v7.z; }
      if (k + 3 < qs) { s0 += v0.w; s1 += v1.w; s2 += v2.w; s3 += v3.w;
                        s4 += v4.w; s5 += v5.w; s6 += v6.w; s7 += v7.w; }
    }
    #pragma unroll
    for (int m = 32; m; m >>= 1) {
      s0 += __shfl_xor(s0, m); s1 += __shfl_xor(s1, m);
      s2 += __shfl_xor(s2, m); s3 += __shfl_xor(s3, m);
      s4 += __shfl_xor(s4, m); s5 += __shfl_xor(s5, m);
      s6 += __shfl_xor(s6, m); s7 += __shfl_xor(s7, m);
    }
    if (lane == 0) {
      *reinterpret_cast<float4*>(&qsum[r0])     = make_float4(s0, s1, s2, s3);
      *reinterpret_cast<float4*>(&qsum[r0 + 4]) = make_float4(s4, s5, s6, s7);
    }
  }
}

// ---------------- kernel 2: finalize means + intra diagonal ----------------
// ONE CLASS PER BLOCK (500 blocks — full-machine grid; the 125-block version
// left half the CUs idle and was ~20 us). Thread f owns feature f; P reads
// coalesced across threads.
__global__ __launch_bounds__(256) void k_means(
    const float* __restrict__ qsum, const int* __restrict__ qsize,
    const float* __restrict__ Psrc, const float* __restrict__ Ptgt,
    const float* __restrict__ CSsrc, const float* __restrict__ CStgt,
    float* __restrict__ MS, float* __restrict__ MT, float* __restrict__ ipart) {
  const int c = blockIdx.x;
  const int f = threadIdx.x;

  float cs_s = 0.f, cs_t = 0.f;
  #pragma unroll
  for (int kc = 0; kc < KC_GEMM; ++kc) {        // wave-uniform -> s_load
    cs_s += CSsrc[kc * 512 + c];
    cs_t += CStgt[kc * 512 + c];
  }
  float num = (float)qsize[c];
  float ns = qsum[(size_t)c * NF + f];
  float nt = 0.f;
  #pragma unroll
  for (int kc = 0; kc < KC_GEMM; ++kc) {
    ns += Psrc[((size_t)kc * NC + c) * NF + f];
    nt += Ptgt[((size_t)kc * NC + c) * NF + f];
  }
  float ms = ns / (num + cs_s + 1e-8f);
  float mt = nt / (cs_t + 1e-8f);
  MS[(size_t)c * NF + f] = ms;
  MT[(size_t)c * NF + f] = mt;

  float d = ms - mt;
  float s = d * d;
  #pragma unroll
  for (int m = 32; m; m >>= 1) s += __shfl_xor(s, m);
  __shared__ float red[4];
  int wid = f >> 6, lane = f & 63;
  if (lane == 0) red[wid] = s;
  __syncthreads();
  if (f == 0) ipart[c] = sqrtf(fmaxf(red[0] + red[1] + red[2] + red[3], 1e-12f));
}

// ---------------- kernel 3: pairwise distances (16x16 tiles) ----------------
#define TC 16
#define NBT 32                              // ceil(500/16)
__global__ __launch_bounds__(256) void k_dist(const float* __restrict__ MS,
                                              float* __restrict__ epart) {
  __shared__ float a[TC][NF + 4];
  __shared__ float b[TC][NF + 4];
  const int bi = blockIdx.x & (NBT - 1);
  const int bj = blockIdx.x >> 5;

  for (int i = threadIdx.x; i < TC * (NF / 4); i += 256) {
    int rr = i >> 6, fq = (i & 63) * 4;
    int c1 = bi * TC + rr;
    int c2 = bj * TC + rr;
    float4 va = (c1 < NC) ? *reinterpret_cast<const float4*>(&MS[(size_t)c1 * NF + fq])
                          : make_float4(0.f, 0.f, 0.f, 0.f);
    float4 vb = (c2 < NC) ? *reinterpret_cast<const float4*>(&MS[(size_t)c2 * NF + fq])
                          : make_float4(0.f, 0.f, 0.f, 0.f);
    *reinterpret_cast<float4*>(&a[rr][fq]) = va;
    *reinterpret_cast<float4*>(&b[rr][fq]) = vb;
  }
  __syncthreads();

  const int i1 = threadIdx.x >> 4, i2 = threadIdx.x & 15;
  float s = 0.f;
  #pragma unroll 8
  for (int fq = 0; fq < NF; fq += 4) {
    float4 va = *reinterpret_cast<const float4*>(&a[i1][fq]);
    float4 vb = *reinterpret_cast<const float4*>(&b[i2][fq]);
    float d0 = va.x - vb.x, d1 = va.y - vb.y, d2 = va.z - vb.z, d3 = va.w - vb.w;
    s = fmaf(d0, d0, s); s = fmaf(d1, d1, s); s = fmaf(d2, d2, s); s = fmaf(d3, d3, s);
  }
  bool valid = (bi * TC + i1 < NC) && (bj * TC + i2 < NC);
  float rr = valid ? sqrtf(fmaxf(s, 1e-12f)) : 0.f;

  #pragma unroll
  for (int m = 32; m; m >>= 1) rr += __shfl_xor(rr, m);
  __shared__ float red[4];
  int wid = threadIdx.x >> 6, lane = threadIdx.x & 63;
  if (lane == 0) red[wid] = rr;
  __syncthreads();
  if (threadIdx.x == 0) epart[blockIdx.x] = red[0] + red[1] + red[2] + red[3];
}

// ---------------- kernel 4: final scalars ----------------
__global__ __launch_bounds__(1024) void k_final(const float* __restrict__ ipart,
                                                const float* __restrict__ epart,
                                                float* __restrict__ out) {
  const int t = threadIdx.x;                // 1024 threads
  float si = (t < NC) ? ipart[t] : 0.f;
  float se = epart[t];
  #pragma unroll
  for (int m = 32; m; m >>= 1) { si += __shfl_xor(si, m); se += __shfl_xor(se, m); }
  __shared__ float ri[16], re[16];
  int wid = t >> 6, lane = t & 63;
  if (lane == 0) { ri[wid] = si; re[wid] = se; }
  __syncthreads();
  if (t == 0) {
    float A = 0.f, B = 0.f;
    #pragma unroll
    for (int w2 = 0; w2 < 16; ++w2) { A += ri[w2]; B += re[w2]; }
    out[0] = A / (float)NC;
    out[1] = B / ((float)NC * (float)NC);
  }
}

extern "C" void kernel_launch(void* const* d_in, const int* in_sizes, int n_in,
                              void* d_out, int out_size, void* d_ws, size_t ws_size,
                              hipStream_t stream) {
  const float* src_x = (const float*)d_in[0];
  const float* tgt_x = (const float*)d_in[1];
  const float* src_y = (const float*)d_in[2];
  const float* tgt_y = (const float*)d_in[3];
  const float* queue = (const float*)d_in[4];
  const int*   qsize = (const int*)d_in[5];
  float* out = (float*)d_out;

  float* ws    = (float*)d_ws;
  float* qsum  = ws;                                   // 128000
  float* Psrc  = qsum + NC * NF;                       // 8 * 128000
  float* Ptgt  = Psrc + (size_t)KC_GEMM * NC * NF;     // 8 * 128000
  float* CSs   = Ptgt + (size_t)KC_GEMM * NC * NF;     // 8 * 512
  float* CSt   = CSs + KC_GEMM * 512;                  // 8 * 512
  float* MS    = CSt + KC_GEMM * 512;                  // 128000
  float* MT    = MS + NC * NF;                         // 128000
  float* ipart = MT + NC * NF;                         // 500
  float* epart = ipart + NC;                           // 1024

  // 1) fused heavy pass: gemm(+colsum) blocks then queue blocks (contiguous)
  k_heavy<<<NB_GEMM + NQB, 256, 0, stream>>>(
      src_x, src_y, Psrc, tgt_x, tgt_y, Ptgt, CSs, CSt, queue, qsize, qsum);

  // 2) means + intra diagonal (one class per block, 500 blocks)
  k_means<<<NC, 256, 0, stream>>>(qsum, qsize, Psrc, Ptgt, CSs, CSt, MS, MT, ipart);

  // 3) pairwise distances
  k_dist<<<NBT * NBT, 256, 0, stream>>>(MS, epart);

  // 4) final reduction
  k_final<<<1, 1024, 0, stream>>>(ipart, epart, out);
}